// Round 11
// baseline (945.572 us; speedup 1.0000x reference)
//
#include <hip/hip_runtime.h>
#include <stdint.h>

// ---------------- types ----------------
typedef __attribute__((ext_vector_type(8))) short bf16x8;   // 8 x bf16 = 4 VGPRs
typedef __attribute__((ext_vector_type(4))) short s16x4;    // 4 x bf16 = 8B
typedef __attribute__((ext_vector_type(4))) float f32x4;
typedef __attribute__((ext_vector_type(4))) unsigned u32x4;

#define AS1 __attribute__((address_space(1)))
#define AS3 __attribute__((address_space(3)))

static __device__ __forceinline__ void gload_lds16(const void* g, void* l) {
  __builtin_amdgcn_global_load_lds((const AS1 unsigned int*)g,
                                   (AS3 unsigned int*)l, 16, 0, 0);
}

// round-to-nearest-even f32 -> bf16 bits
static __device__ __forceinline__ short f2bs(float f) {
  unsigned u = __builtin_bit_cast(unsigned, f);
  unsigned r = (u + 0x7fffu + ((u >> 16) & 1u)) >> 16;
  return (short)r;
}
static __device__ __forceinline__ float bs2f(short s) {
  unsigned u = ((unsigned)(unsigned short)s) << 16;
  return __builtin_bit_cast(float, u);
}

static __device__ __forceinline__ float sigmoid_f(float x) {
  return 1.0f / (1.0f + __expf(-x));
}
static __device__ __forceinline__ float tanh_f(float x) {
  float ax = fabsf(x);
  float e  = __expf(-2.0f * ax);
  float t  = (1.0f - e) / (1.0f + e);
  return copysignf(t, x);
}

// constants
#define BATCH 256
#define HID   512
#define STEPS 256
#define G3    1536   // 3*HID

// ---------------- fp32 -> bf16 convert (weights) ----------------
__global__ __launch_bounds__(256) void convert_kernel(const float* __restrict__ src,
                                                      short* __restrict__ dst, int n4) {
  int i = blockIdx.x * 256 + threadIdx.x;
  if (i < n4) {
    float4 v = *(const float4*)(src + (size_t)i * 4);
    s16x4 o;
    o[0] = f2bs(v.x); o[1] = f2bs(v.y); o[2] = f2bs(v.z); o[3] = f2bs(v.w);
    *(s16x4*)(dst + (size_t)i * 4) = o;
  }
}

// ---------------- x[b][i][s] f32  ->  xT[s][b][i] bf16 ----------------
__global__ __launch_bounds__(256) void transpose_kernel(const float* __restrict__ x,
                                                        short* __restrict__ xT) {
  int bx = blockIdx.x;
  int st = bx & 7, it = (bx >> 3) & 15, b = bx >> 7;
  int s0 = st * 32, i0 = it * 32;
  int tid = threadIdx.x;
  __shared__ float tile[32][33];
  int il = tid >> 3, s4 = (tid & 7) * 4;
  float4 v = *(const float4*)(x + (size_t)b * 131072 + (size_t)(i0 + il) * 256 + s0 + s4);
  tile[il][s4 + 0] = v.x; tile[il][s4 + 1] = v.y;
  tile[il][s4 + 2] = v.z; tile[il][s4 + 3] = v.w;
  __syncthreads();
  int sl = tid >> 3, iv = (tid & 7) * 4;
  s16x4 o;
  o[0] = f2bs(tile[iv + 0][sl]); o[1] = f2bs(tile[iv + 1][sl]);
  o[2] = f2bs(tile[iv + 2][sl]); o[3] = f2bs(tile[iv + 3][sl]);
  *(s16x4*)(xT + (size_t)(s0 + sl) * 131072 + (size_t)b * 512 + i0 + iv) = o;
}

// ---------------- fused persistent GRU scan (phase1 FUSED IN) ---------------
// R11: phase1 is DELETED. Three consecutive nulls (R9 swizzle, R10 dbuf)
// proved the separate 103-GFLOP input-projection GEMM (~290us at ~350 TF) is
// not improvable in its launch regime; meanwhile the scan has ~1.5us/step of
// pure idle detect-wait. The x-projection has NO dependency on h, so each
// block computes its own gi slice (16 rows x 96 gate-cols) for step t+1
// BEFORE polling step t — entirely inside the former idle window. Also kills
// the 400MB gi HBM round-trip.
// Resources: persistent 1 block/CU -> VGPR free to 512: Wih fragments in
// registers (Wf[2][16], 128 VGPR) beside Whh's Bf. launch_bounds(256,1).
// x tiles: x_lds[2] (16KB each), staged by global_load_lds with an XOR
// involution (byte bits 4-6 ^= row bits 0-2) applied BOTH at the per-lane
// global source (content lands swizzled; dest stays linear as gload_lds
// requires) and at the MFMA A-frag read -> 2-way max bank aliasing (free).
// gi crosses waves via parity-double-buffered gi_lds (mirrors gh_lds).
// Step t: [bar#0] stage x(t+2)->x_lds[t&1]; XGEMM gi(t+1)->gi_lds[(t+1)&1];
//         poll(t) (vmcnt(0) drains x-stage); stash h; [bar#1] gh-MFMA;
//         [bar#2] cell reads gh_lds + gi_lds[t&1] (+separate bih/bhh — only
//         r/z biases could fold, n-gate needs them split); publish tag t+1.
// Hazards: every LDS reuse pair is separated by a raw barrier carrying
// lgkmcnt(0) (reads retired before overwrite); x_lds parity reuse distance
// is 2 steps; gi_lds write[(t+1)&1]@top(t) vs cell(t-1) read same parity is
// fenced by bar#0. Poll/publish protocol byte-identical to R6 (measured
// optimum; R8 proved cadence is LLC-contention-limited).
__global__ __launch_bounds__(256, 1) void scan_kernel(const short* __restrict__ xT,
                                                      const short* __restrict__ Wih,
                                                      const short* __restrict__ Whh,
                                                      const float* __restrict__ bias_ih,
                                                      const float* __restrict__ bias_hh,
                                                      unsigned* __restrict__ hbuf,
                                                      float* __restrict__ hmaster) {
  const int CH = 256;
  int bid = blockIdx.x;
  int xcd = bid & 7, slot = bid >> 3;
  int group = xcd + 8 * (slot >> 4);
  int j = slot & 15;
  int tid = threadIdx.x;
  int w = tid >> 6, lane = tid & 63;
  int lm = lane & 15, q = lane >> 4;
  int grow = group * 16;

  __shared__ __align__(16) short h_lds[16 * 520];   // padded rows 512+8
  __shared__ __align__(16) short x_lds[2][8192];    // swizzled content, linear dest
  __shared__ float gh_lds[16][100];
  __shared__ float gi_lds[2][16][100];
  __shared__ float h_loc[512];                      // [16][32] fp32 state
  __shared__ float bih_s[96], bhh_s[96];

  // weight fragments: wave w (<3) -> gate w, 2 N-tiles x 16 K-steps each
  bf16x8 Bf[2][16];   // W_hh
  bf16x8 Wf[2][16];   // W_ih
  if (w < 3) {
#pragma unroll
    for (int tau = 0; tau < 2; ++tau)
#pragma unroll
      for (int kt = 0; kt < 16; ++kt) {
        int row = w * 512 + j * 32 + tau * 16 + lm;
        Bf[tau][kt] = *(const bf16x8*)(Whh + (size_t)row * 512 + kt * 32 + q * 8);
        Wf[tau][kt] = *(const bf16x8*)(Wih + (size_t)row * 512 + kt * 32 + q * 8);
      }
  }
  if (tid < 96) {
    int g = (tid >> 5) * 512 + j * 32 + (tid & 31);
    bih_s[tid] = bias_ih[g];
    bhh_s[tid] = bias_hh[g];
  }
  h_loc[tid] = 0.0f;
  h_loc[tid + 256] = 0.0f;

  // x staging geometry (step-independent). dest byte D = c*4096 + tid*16 is
  // LINEAR; logical L = D ^ (((D>>10)&7)<<4) -> row r = c*4+w, swizzled col.
  int xr[4], xc[4];
#pragma unroll
  for (int c = 0; c < 4; ++c) {
    int rr_ = c * 4 + w;
    xr[c] = rr_;
    xc[c] = ((lane * 16) ^ ((rr_ & 7) << 4)) >> 1;   // shorts
  }

#define XSTAGE(s, par) do {                                                  \
    const short* xsb = xT + (size_t)(s) * 131072;                            \
    _Pragma("unroll")                                                        \
    for (int c = 0; c < 4; ++c)                                              \
      gload_lds16(xsb + (size_t)(grow + xr[c]) * 512 + xc[c],                \
                  &x_lds[par][c * 2048 + tid * 8]);                          \
  } while (0)

  // A-frag read: logical byte S = lm*1024 + kt*64 + q*16, read at
  // S ^ ((lm&7)<<4); in shorts: lm*512 + ((kt*32+q*8) ^ ((lm&7)<<3)).
#define XGEMM(pn) do {                                                       \
    f32x4 a0 = {0.f,0.f,0.f,0.f}, a1 = {0.f,0.f,0.f,0.f};                    \
    f32x4 a2 = {0.f,0.f,0.f,0.f}, a3 = {0.f,0.f,0.f,0.f};                    \
    _Pragma("unroll")                                                        \
    for (int kt = 0; kt < 8; ++kt) {                                         \
      bf16x8 a = *(const bf16x8*)(&x_lds[pn][lm * 512 +                      \
                      ((kt * 32 + q * 8) ^ ((lm & 7) << 3))]);               \
      a0 = __builtin_amdgcn_mfma_f32_16x16x32_bf16(a, Wf[0][kt], a0, 0, 0, 0); \
      a1 = __builtin_amdgcn_mfma_f32_16x16x32_bf16(a, Wf[1][kt], a1, 0, 0, 0); \
    }                                                                        \
    _Pragma("unroll")                                                        \
    for (int kt = 8; kt < 16; ++kt) {                                        \
      bf16x8 a = *(const bf16x8*)(&x_lds[pn][lm * 512 +                      \
                      ((kt * 32 + q * 8) ^ ((lm & 7) << 3))]);               \
      a2 = __builtin_amdgcn_mfma_f32_16x16x32_bf16(a, Wf[0][kt], a2, 0, 0, 0); \
      a3 = __builtin_amdgcn_mfma_f32_16x16x32_bf16(a, Wf[1][kt], a3, 0, 0, 0); \
    }                                                                        \
    _Pragma("unroll")                                                        \
    for (int r = 0; r < 4; ++r) {                                            \
      gi_lds[pn][q * 4 + r][w * 32 + lm]      = a0[r] + a2[r];               \
      gi_lds[pn][q * 4 + r][w * 32 + 16 + lm] = a1[r] + a3[r];               \
    }                                                                        \
  } while (0)

  // prologue: x(0)->x_lds[0], x(1)->x_lds[1]; gi(0)->gi_lds[0]
  XSTAGE(0, 0);
  XSTAGE(1, 1);
  asm volatile("s_waitcnt vmcnt(0)" ::: "memory");
  __syncthreads();
  if (w < 3) XGEMM(0);
  __syncthreads();

  // poll geometry (R1/R6, coalesced): thread covers 8 chunks of 16B
  unsigned o0 = (unsigned)tid * 16u;
  const int r0 = tid >> 7;
  const int colb = (tid & 127) * 4;
  short* lp = h_lds + r0 * 520 + colb;        // +c*1040 shorts per chunk
  unsigned* grp_base = hbuf + (size_t)group * 8192;

  for (int t = 0; t < CH; ++t) {
    int p = t & 1;
    const unsigned* src = grp_base + (size_t)p * 131072;
    unsigned want = (unsigned)t;

    // barrier #0: cell(t-1) LDS reads retired before gi/x writes below
    asm volatile("s_waitcnt lgkmcnt(0)\n\ts_barrier" ::: "memory");
    __builtin_amdgcn_sched_barrier(0);

    // stage x(t+2) -> x_lds[t&1] (read at top of t+1; drained by poll vmcnt)
    {
      int s = (t + 2 < CH) ? (t + 2) : (CH - 1);
      XSTAGE(s, p);
    }
    // x-GEMM gi(t+1) from x_lds[(t+1)&1] (staged at t-1) — runs in the
    // former idle detect window, off the sync critical path
    if (w < 3 && t + 1 < CH) XGEMM((t + 1) & 1);

    // ---- poll: R6-exact (bulk 8-load, vmcnt(0) inside asm, s_sleep pacing)
    u32x4 v0, v1, v2, v3, v4, v5, v6, v7;
    int spin = 0;
    for (;;) {
      asm volatile(
          "global_load_dwordx4 %0, %8, %16 sc0 sc1\n\t"
          "global_load_dwordx4 %1, %9, %16 sc0 sc1\n\t"
          "global_load_dwordx4 %2, %10, %16 sc0 sc1\n\t"
          "global_load_dwordx4 %3, %11, %16 sc0 sc1\n\t"
          "global_load_dwordx4 %4, %12, %16 sc0 sc1\n\t"
          "global_load_dwordx4 %5, %13, %16 sc0 sc1\n\t"
          "global_load_dwordx4 %6, %14, %16 sc0 sc1\n\t"
          "global_load_dwordx4 %7, %15, %16 sc0 sc1\n\t"
          "s_waitcnt vmcnt(0)"
          : "=&v"(v0), "=&v"(v1), "=&v"(v2), "=&v"(v3),
            "=&v"(v4), "=&v"(v5), "=&v"(v6), "=&v"(v7)
          : "v"(o0), "v"(o0 + 4096u), "v"(o0 + 8192u), "v"(o0 + 12288u),
            "v"(o0 + 16384u), "v"(o0 + 20480u), "v"(o0 + 24576u), "v"(o0 + 28672u),
            "s"(src)
          : "memory");
      unsigned d;
      d  = (v0[0] ^ want) | (v0[1] ^ want) | (v0[2] ^ want) | (v0[3] ^ want);
      d |= (v1[0] ^ want) | (v1[1] ^ want) | (v1[2] ^ want) | (v1[3] ^ want);
      d |= (v2[0] ^ want) | (v2[1] ^ want) | (v2[2] ^ want) | (v2[3] ^ want);
      d |= (v3[0] ^ want) | (v3[1] ^ want) | (v3[2] ^ want) | (v3[3] ^ want);
      d |= (v4[0] ^ want) | (v4[1] ^ want) | (v4[2] ^ want) | (v4[3] ^ want);
      d |= (v5[0] ^ want) | (v5[1] ^ want) | (v5[2] ^ want) | (v5[3] ^ want);
      d |= (v6[0] ^ want) | (v6[1] ^ want) | (v6[2] ^ want) | (v6[3] ^ want);
      d |= (v7[0] ^ want) | (v7[1] ^ want) | (v7[2] ^ want) | (v7[3] ^ want);
      if (((d & 0xffffu) == 0u) || (++spin > (1 << 16))) break;
      __builtin_amdgcn_s_sleep(1);
    }

    // stash fresh h (strip tags) into MFMA staging layout
#define STASH(vv, c)                                                         \
    {                                                                        \
      s16x4 o_;                                                              \
      o_[0] = (short)(vv[0] >> 16); o_[1] = (short)(vv[1] >> 16);            \
      o_[2] = (short)(vv[2] >> 16); o_[3] = (short)(vv[3] >> 16);            \
      *(s16x4*)(lp + (c) * 1040) = o_;                                       \
    }
    STASH(v0, 0) STASH(v1, 1) STASH(v2, 2) STASH(v3, 3)
    STASH(v4, 4) STASH(v5, 5) STASH(v6, 6) STASH(v7, 7)
#undef STASH

    // barrier #1: h_lds stash -> gh-MFMA reads (LDS ordering only)
    asm volatile("s_waitcnt lgkmcnt(0)\n\ts_barrier" ::: "memory");
    __builtin_amdgcn_sched_barrier(0);

    // gh-MFMA (unchanged R6 structure)
    if (w < 3) {
      f32x4 a0 = {0.f,0.f,0.f,0.f}, a1 = {0.f,0.f,0.f,0.f};
      f32x4 a2 = {0.f,0.f,0.f,0.f}, a3 = {0.f,0.f,0.f,0.f};
#pragma unroll
      for (int kt = 0; kt < 8; ++kt) {
        bf16x8 a = *(const bf16x8*)(h_lds + lm * 520 + kt * 32 + q * 8);
        a0 = __builtin_amdgcn_mfma_f32_16x16x32_bf16(a, Bf[0][kt], a0, 0, 0, 0);
        a1 = __builtin_amdgcn_mfma_f32_16x16x32_bf16(a, Bf[1][kt], a1, 0, 0, 0);
      }
#pragma unroll
      for (int kt = 8; kt < 16; ++kt) {
        bf16x8 a = *(const bf16x8*)(h_lds + lm * 520 + kt * 32 + q * 8);
        a2 = __builtin_amdgcn_mfma_f32_16x16x32_bf16(a, Bf[0][kt], a2, 0, 0, 0);
        a3 = __builtin_amdgcn_mfma_f32_16x16x32_bf16(a, Bf[1][kt], a3, 0, 0, 0);
      }
#pragma unroll
      for (int r = 0; r < 4; ++r) {
        gh_lds[q * 4 + r][w * 32 + lm]      = a0[r] + a2[r];
        gh_lds[q * 4 + r][w * 32 + 16 + lm] = a1[r] + a3[r];
      }
    }
    // barrier #2: gh_lds/gi_lds writes -> cell reads
    asm volatile("s_waitcnt lgkmcnt(0)\n\ts_barrier" ::: "memory");
    __builtin_amdgcn_sched_barrier(0);

    // elementwise GRU cell + tagged publish
    unsigned tagp = (unsigned)(t + 1);
    unsigned* dstb = grp_base + (size_t)(1 - p) * 131072;
    {
      int i0 = tid;
      int r = i0 >> 5, cc = i0 & 31;
      float cgr = gi_lds[p][r][cc]      + bih_s[cc];
      float cgz = gi_lds[p][r][32 + cc] + bih_s[32 + cc];
      float cgn = gi_lds[p][r][64 + cc] + bih_s[64 + cc];
      float hr = gh_lds[r][cc]      + bhh_s[cc];
      float hz = gh_lds[r][32 + cc] + bhh_s[32 + cc];
      float hn = gh_lds[r][64 + cc] + bhh_s[64 + cc];
      float rr = sigmoid_f(cgr + hr);
      float zz = sigmoid_f(cgz + hz);
      float nn = tanh_f(cgn + rr * hn);
      float hv = (1.0f - zz) * nn + zz * h_loc[i0];
      h_loc[i0] = hv;
      unsigned val = (((unsigned)(unsigned short)f2bs(hv)) << 16) | tagp;
      unsigned* dp = dstb + r * 512 + j * 32 + cc;
      asm volatile("global_store_dword %0, %1, off sc0 sc1" :: "v"(dp), "v"(val) : "memory");
    }
    {
      int i1 = tid + 256;
      int r = i1 >> 5, cc = i1 & 31;
      float cgr = gi_lds[p][r][cc]      + bih_s[cc];
      float cgz = gi_lds[p][r][32 + cc] + bih_s[32 + cc];
      float cgn = gi_lds[p][r][64 + cc] + bih_s[64 + cc];
      float hr = gh_lds[r][cc]      + bhh_s[cc];
      float hz = gh_lds[r][32 + cc] + bhh_s[32 + cc];
      float hn = gh_lds[r][64 + cc] + bhh_s[64 + cc];
      float rr = sigmoid_f(cgr + hr);
      float zz = sigmoid_f(cgz + hz);
      float nn = tanh_f(cgn + rr * hn);
      float hv = (1.0f - zz) * nn + zz * h_loc[i1];
      h_loc[i1] = hv;
      unsigned val = (((unsigned)(unsigned short)f2bs(hv)) << 16) | tagp;
      unsigned* dp = dstb + r * 512 + j * 32 + cc;
      asm volatile("global_store_dword %0, %1, off sc0 sc1" :: "v"(dp), "v"(val) : "memory");
    }
  }
#undef XSTAGE
#undef XGEMM

  // drain any leftover staging loads before teardown
  asm volatile("s_waitcnt vmcnt(0)" ::: "memory");

  // final fp32 state -> out
#pragma unroll
  for (int u = 0; u < 2; ++u) {
    int idx = tid + u * 256;
    int r = idx >> 5, cc = idx & 31;
    hmaster[(size_t)(grow + r) * 512 + j * 32 + cc] = h_loc[idx];
  }
}

// ---------------- host ----------------
extern "C" void kernel_launch(void* const* d_in, const int* in_sizes, int n_in,
                              void* d_out, int out_size, void* d_ws, size_t ws_size,
                              hipStream_t stream) {
  const float* x   = (const float*)d_in[0];
  const float* Wih = (const float*)d_in[1];
  const float* Whh = (const float*)d_in[2];
  const float* bih = (const float*)d_in[3];
  const float* bhh = (const float*)d_in[4];
  float* out = (float*)d_out;
  char* ws = (char*)d_ws;

  const size_t XT_BYTES   = (size_t)256 * 256 * 512 * 2;  // 64 MiB
  const size_t W_BYTES    = (size_t)1536 * 512 * 2;       // 1.5 MiB
  const size_t HBUF_BYTES = (size_t)2 * 256 * 512 * 4;    // 1 MiB (tagged dwords)

  size_t off = 0;
  short* xT = (short*)(ws + off);          off += XT_BYTES;
  short* WihB = (short*)(ws + off);        off += W_BYTES;
  short* WhhB = (short*)(ws + off);        off += W_BYTES;
  unsigned* hbuf = (unsigned*)(ws + off);

  hipMemsetAsync(hbuf, 0, HBUF_BYTES, stream);

  convert_kernel<<<768, 256, 0, stream>>>(Wih, WihB, 196608);
  convert_kernel<<<768, 256, 0, stream>>>(Whh, WhhB, 196608);
  transpose_kernel<<<32768, 256, 0, stream>>>(x, xT);

  scan_kernel<<<256, 256, 0, stream>>>(xT, WihB, WhhB, bih, bhh, hbuf, out);
}